// Round 1
// baseline (838.678 us; speedup 1.0000x reference)
//
#include <hip/hip_runtime.h>

#define F1 128
#define F2 64

// ---------------- CSR build ----------------

__global__ void k_hist(const int* __restrict__ colv, int* __restrict__ counts, int E) {
    int e = blockIdx.x * blockDim.x + threadIdx.x;
    if (e < E) atomicAdd(&counts[colv[e]], 1);
}

__global__ __launch_bounds__(1024) void k_scan1(const int* __restrict__ counts,
                                                int* __restrict__ excl,
                                                int* __restrict__ partials, int N) {
    __shared__ int s[1024];
    int i = blockIdx.x * 1024 + threadIdx.x;
    int v = (i < N) ? counts[i] : 0;
    s[threadIdx.x] = v;
    __syncthreads();
    for (int d = 1; d < 1024; d <<= 1) {
        int t = (threadIdx.x >= (unsigned)d) ? s[threadIdx.x - d] : 0;
        __syncthreads();
        s[threadIdx.x] += t;
        __syncthreads();
    }
    if (i < N) excl[i] = s[threadIdx.x] - v;   // exclusive scan within block
    if (threadIdx.x == 1023) partials[blockIdx.x] = s[1023];
}

__global__ void k_scan2(int* partials, int P, int* rowptr_last) {
    if (blockIdx.x == 0 && threadIdx.x == 0) {
        int run = 0;
        for (int b = 0; b < P; b++) { int t = partials[b]; partials[b] = run; run += t; }
        *rowptr_last = run;   // == E
    }
}

__global__ void k_scan3(int* __restrict__ rowptr, int* __restrict__ cursor,
                        const int* __restrict__ partials, int N) {
    int i = blockIdx.x * blockDim.x + threadIdx.x;
    if (i < N) {
        int v = rowptr[i] + partials[i >> 10];
        rowptr[i] = v;
        cursor[i] = v;
    }
}

__global__ void k_fill(const int* __restrict__ rowv, const int* __restrict__ colv,
                       int* __restrict__ cursor, int* __restrict__ adj, int E) {
    int e = blockIdx.x * blockDim.x + threadIdx.x;
    if (e < E) {
        int c = colv[e];
        int pos = atomicAdd(&cursor[c], 1);
        adj[pos] = rowv[e];
    }
}

__global__ void k_dis(const int* __restrict__ counts, float* __restrict__ dis, int N) {
    int i = blockIdx.x * blockDim.x + threadIdx.x;
    if (i < N) dis[i] = rsqrtf((float)(counts[i] + 1));   // +1 = self loop; deg>=1 always
}

// ---------------- GEMM 1: g1 = dis[row] * (x @ W1), W1 128x128 in LDS ----------------

__global__ __launch_bounds__(256) void k_gemm1(const float* __restrict__ x,
                                               const float* __restrict__ W,
                                               const float* __restrict__ dis,
                                               float* __restrict__ g, int N) {
    __shared__ float sW[F1 * F1];   // 64 KB
    {
        const float4* W4 = (const float4*)W;
        float4* s4 = (float4*)sW;
        for (int i = threadIdx.x; i < F1 * F1 / 4; i += 256) s4[i] = W4[i];
    }
    __syncthreads();
    int wave = threadIdx.x >> 6, lane = threadIdx.x & 63;
    int groups = (N + 3) >> 2;
    int wid = blockIdx.x * 4 + wave;
    int nw = gridDim.x * 4;
    for (int grp = wid; grp < groups; grp += nw) {
        int base = grp * 4;
        int r0 = base, r1 = min(base + 1, N - 1), r2 = min(base + 2, N - 1), r3 = min(base + 3, N - 1);
        float a00 = 0, a01 = 0, a10 = 0, a11 = 0, a20 = 0, a21 = 0, a30 = 0, a31 = 0;
        const float* x0 = x + (size_t)r0 * F1;
        const float* x1 = x + (size_t)r1 * F1;
        const float* x2 = x + (size_t)r2 * F1;
        const float* x3 = x + (size_t)r3 * F1;
        for (int k = 0; k < F1; k += 4) {
            float4 xv0 = *(const float4*)(x0 + k);
            float4 xv1 = *(const float4*)(x1 + k);
            float4 xv2 = *(const float4*)(x2 + k);
            float4 xv3 = *(const float4*)(x3 + k);
#pragma unroll
            for (int kk = 0; kk < 4; kk++) {
                float2 wv = *((const float2*)&sW[(k + kk) * F1] + lane);
                float xs;
                xs = ((const float*)&xv0)[kk]; a00 += xs * wv.x; a01 += xs * wv.y;
                xs = ((const float*)&xv1)[kk]; a10 += xs * wv.x; a11 += xs * wv.y;
                xs = ((const float*)&xv2)[kk]; a20 += xs * wv.x; a21 += xs * wv.y;
                xs = ((const float*)&xv3)[kk]; a30 += xs * wv.x; a31 += xs * wv.y;
            }
        }
        float d;
        if (base + 0 < N) { d = dis[base + 0]; *((float2*)&g[(size_t)(base + 0) * F1] + lane) = make_float2(a00 * d, a01 * d); }
        if (base + 1 < N) { d = dis[base + 1]; *((float2*)&g[(size_t)(base + 1) * F1] + lane) = make_float2(a10 * d, a11 * d); }
        if (base + 2 < N) { d = dis[base + 2]; *((float2*)&g[(size_t)(base + 2) * F1] + lane) = make_float2(a20 * d, a21 * d); }
        if (base + 3 < N) { d = dis[base + 3]; *((float2*)&g[(size_t)(base + 3) * F1] + lane) = make_float2(a30 * d, a31 * d); }
    }
}

// ---------------- Aggregation 1: z = relu(dis[i]*(g1[i] + sum g1[src]) + b1) ----------------

__global__ __launch_bounds__(256) void k_agg1(const float* __restrict__ g1,
                                              const int* __restrict__ rowptr,
                                              const int* __restrict__ adj,
                                              const float* __restrict__ dis,
                                              const float* __restrict__ b,
                                              float* __restrict__ z, int N) {
    int node = blockIdx.x * 4 + (threadIdx.x >> 6);
    if (node >= N) return;
    int lane = threadIdx.x & 63;
    const float2* gsrc = (const float2*)g1;   // row stride = 64 float2
    float2 acc = gsrc[(size_t)node * 64 + lane];   // self-loop term
    int s = rowptr[node], e = rowptr[node + 1];
    int j = s;
    for (; j + 1 < e; j += 2) {
        int s0 = adj[j], s1 = adj[j + 1];
        float2 v0 = gsrc[(size_t)s0 * 64 + lane];
        float2 v1 = gsrc[(size_t)s1 * 64 + lane];
        acc.x += v0.x + v1.x;
        acc.y += v0.y + v1.y;
    }
    if (j < e) {
        float2 v = gsrc[(size_t)adj[j] * 64 + lane];
        acc.x += v.x; acc.y += v.y;
    }
    float d = dis[node];
    float2 bb = ((const float2*)b)[lane];
    float2 o;
    o.x = fmaxf(d * acc.x + bb.x, 0.0f);
    o.y = fmaxf(d * acc.y + bb.y, 0.0f);
    ((float2*)z)[(size_t)node * 64 + lane] = o;
}

// ---------------- GEMM 2: g2 = dis[row] * (z @ W2), W2 128x64 in LDS ----------------

__global__ __launch_bounds__(256) void k_gemm2(const float* __restrict__ z,
                                               const float* __restrict__ W,
                                               const float* __restrict__ dis,
                                               float* __restrict__ g, int N) {
    __shared__ float sW[F1 * F2];   // 32 KB
    {
        const float4* W4 = (const float4*)W;
        float4* s4 = (float4*)sW;
        for (int i = threadIdx.x; i < F1 * F2 / 4; i += 256) s4[i] = W4[i];
    }
    __syncthreads();
    int wave = threadIdx.x >> 6, lane = threadIdx.x & 63;
    int groups = (N + 3) >> 2;
    int wid = blockIdx.x * 4 + wave;
    int nw = gridDim.x * 4;
    for (int grp = wid; grp < groups; grp += nw) {
        int base = grp * 4;
        int r0 = base, r1 = min(base + 1, N - 1), r2 = min(base + 2, N - 1), r3 = min(base + 3, N - 1);
        float a0 = 0, a1 = 0, a2 = 0, a3 = 0;
        const float* x0 = z + (size_t)r0 * F1;
        const float* x1 = z + (size_t)r1 * F1;
        const float* x2 = z + (size_t)r2 * F1;
        const float* x3 = z + (size_t)r3 * F1;
        for (int k = 0; k < F1; k += 4) {
            float4 xv0 = *(const float4*)(x0 + k);
            float4 xv1 = *(const float4*)(x1 + k);
            float4 xv2 = *(const float4*)(x2 + k);
            float4 xv3 = *(const float4*)(x3 + k);
#pragma unroll
            for (int kk = 0; kk < 4; kk++) {
                float wv = sW[(k + kk) * F2 + lane];
                a0 += ((const float*)&xv0)[kk] * wv;
                a1 += ((const float*)&xv1)[kk] * wv;
                a2 += ((const float*)&xv2)[kk] * wv;
                a3 += ((const float*)&xv3)[kk] * wv;
            }
        }
        if (base + 0 < N) g[(size_t)(base + 0) * F2 + lane] = a0 * dis[base + 0];
        if (base + 1 < N) g[(size_t)(base + 1) * F2 + lane] = a1 * dis[base + 1];
        if (base + 2 < N) g[(size_t)(base + 2) * F2 + lane] = a2 * dis[base + 2];
        if (base + 3 < N) g[(size_t)(base + 3) * F2 + lane] = a3 * dis[base + 3];
    }
}

// ---------------- Aggregation 2: out = dis[i]*(g2[i] + sum g2[src]) + b2 ----------------

__global__ __launch_bounds__(256) void k_agg2(const float* __restrict__ g,
                                              const int* __restrict__ rowptr,
                                              const int* __restrict__ adj,
                                              const float* __restrict__ dis,
                                              const float* __restrict__ b,
                                              float* __restrict__ out, int N) {
    int node = blockIdx.x * 4 + (threadIdx.x >> 6);
    if (node >= N) return;
    int lane = threadIdx.x & 63;
    float acc = g[(size_t)node * F2 + lane];   // self-loop term
    int s = rowptr[node], e = rowptr[node + 1];
    int j = s;
    for (; j + 1 < e; j += 2) {
        int s0 = adj[j], s1 = adj[j + 1];
        acc += g[(size_t)s0 * F2 + lane] + g[(size_t)s1 * F2 + lane];
    }
    if (j < e) acc += g[(size_t)adj[j] * F2 + lane];
    out[(size_t)node * F2 + lane] = dis[node] * acc + b[lane];
}

// ---------------- launch ----------------

extern "C" void kernel_launch(void* const* d_in, const int* in_sizes, int n_in,
                              void* d_out, int out_size, void* d_ws, size_t ws_size,
                              hipStream_t stream) {
    const float* x  = (const float*)d_in[0];
    const int*   ei = (const int*)d_in[1];
    const float* W1 = (const float*)d_in[2];
    const float* b1 = (const float*)d_in[3];
    const float* W2 = (const float*)d_in[4];
    const float* b2 = (const float*)d_in[5];
    float* out = (float*)d_out;

    const int N = in_sizes[0] / F1;
    const int E = in_sizes[1] / 2;
    const int* rowv = ei;        // sources
    const int* colv = ei + E;    // targets

    char* ws = (char*)d_ws;
    size_t off = 0;
    auto take = [&](size_t bytes) -> void* {
        void* p = ws + off;
        off += (bytes + 255) & ~(size_t)255;
        return p;
    };
    float* g1      = (float*)take((size_t)N * F1 * 4);   // 51.2 MB
    float* z       = (float*)take((size_t)N * F1 * 4);   // 51.2 MB
    float* g2      = g1;                                  // g1 dead after agg1 -> reuse
    float* dis     = (float*)take((size_t)N * 4);
    int*   counts  = (int*)take((size_t)N * 4);
    int*   rowptr  = (int*)take((size_t)(N + 1) * 4);
    int*   cursor  = (int*)take((size_t)N * 4);
    int*   partials= (int*)take(1024 * 4);
    int*   adj     = (int*)take((size_t)E * 4);          // 6.4 MB

    hipMemsetAsync(counts, 0, (size_t)N * 4, stream);

    k_hist<<<(E + 255) / 256, 256, 0, stream>>>(colv, counts, E);
    int P = (N + 1023) / 1024;
    k_scan1<<<P, 1024, 0, stream>>>(counts, rowptr, partials, N);
    k_scan2<<<1, 64, 0, stream>>>(partials, P, rowptr + N);
    k_scan3<<<(N + 255) / 256, 256, 0, stream>>>(rowptr, cursor, partials, N);
    k_fill<<<(E + 255) / 256, 256, 0, stream>>>(rowv, colv, cursor, adj, E);
    k_dis<<<(N + 255) / 256, 256, 0, stream>>>(counts, dis, N);

    k_gemm1<<<512, 256, 0, stream>>>(x, W1, dis, g1, N);
    k_agg1<<<(N + 3) / 4, 256, 0, stream>>>(g1, rowptr, adj, dis, b1, z, N);
    k_gemm2<<<1024, 256, 0, stream>>>(z, W2, dis, g2, N);
    k_agg2<<<(N + 3) / 4, 256, 0, stream>>>(g2, rowptr, adj, dis, b2, out, N);
}

// Round 2
// 683.649 us; speedup vs baseline: 1.2268x; 1.2268x over previous
//
#include <hip/hip_runtime.h>

#define F1 128
#define F2 64

// ---------------- CSR build ----------------

__global__ void k_hist(const int* __restrict__ colv, int* __restrict__ counts, int E) {
    int e = blockIdx.x * blockDim.x + threadIdx.x;
    if (e < E) atomicAdd(&counts[colv[e]], 1);
}

__global__ __launch_bounds__(1024) void k_scan1(const int* __restrict__ counts,
                                                int* __restrict__ excl,
                                                int* __restrict__ partials, int N) {
    __shared__ int s[1024];
    int i = blockIdx.x * 1024 + threadIdx.x;
    int v = (i < N) ? counts[i] : 0;
    s[threadIdx.x] = v;
    __syncthreads();
    for (int d = 1; d < 1024; d <<= 1) {
        int t = (threadIdx.x >= (unsigned)d) ? s[threadIdx.x - d] : 0;
        __syncthreads();
        s[threadIdx.x] += t;
        __syncthreads();
    }
    if (i < N) excl[i] = s[threadIdx.x] - v;   // exclusive scan within block
    if (threadIdx.x == 1023) partials[blockIdx.x] = s[1023];
}

__global__ void k_scan2(int* partials, int P, int* rowptr_last) {
    if (blockIdx.x == 0 && threadIdx.x == 0) {
        int run = 0;
        for (int b = 0; b < P; b++) { int t = partials[b]; partials[b] = run; run += t; }
        *rowptr_last = run;   // == E
    }
}

__global__ void k_scan3(int* __restrict__ rowptr, int* __restrict__ cursor,
                        const int* __restrict__ partials, int N) {
    int i = blockIdx.x * blockDim.x + threadIdx.x;
    if (i < N) {
        int v = rowptr[i] + partials[i >> 10];
        rowptr[i] = v;
        cursor[i] = v;
    }
}

__global__ void k_fill(const int* __restrict__ rowv, const int* __restrict__ colv,
                       int* __restrict__ cursor, int* __restrict__ adj, int E) {
    int e = blockIdx.x * blockDim.x + threadIdx.x;
    if (e < E) {
        int c = colv[e];
        int pos = atomicAdd(&cursor[c], 1);
        adj[pos] = rowv[e];
    }
}

__global__ void k_dis(const int* __restrict__ counts, float* __restrict__ dis, int N) {
    int i = blockIdx.x * blockDim.x + threadIdx.x;
    if (i < N) dis[i] = rsqrtf((float)(counts[i] + 1));   // +1 = self loop; deg>=1 always
}

// ---------------- GEMM 1: g1 = dis[row] * (x @ W1), W1 128x128 in LDS ----------------
// block=512 (8 waves), LDS 64KB -> 2 blocks/CU = 4 waves/SIMD. VGPR cap 128.
// Row pointers forced wave-uniform (readfirstlane) so x loads can scalarize to s_load.

__global__ __launch_bounds__(512, 4) void k_gemm1(const float* __restrict__ x,
                                                  const float* __restrict__ W,
                                                  const float* __restrict__ dis,
                                                  float* __restrict__ g, int N) {
    __shared__ float sW[F1 * F1];   // 64 KB
    {
        const float4* W4 = (const float4*)W;
        float4* s4 = (float4*)sW;
        for (int i = threadIdx.x; i < F1 * F1 / 4; i += 512) s4[i] = W4[i];
    }
    __syncthreads();
    int lane = threadIdx.x & 63;
    int wid = __builtin_amdgcn_readfirstlane(blockIdx.x * 8 + (threadIdx.x >> 6));
    int nw = gridDim.x * 8;
    int groups = (N + 3) >> 2;
    for (int grp = wid; grp < groups; grp += nw) {
        int base = grp * 4;
        int r0 = base;
        int r1 = min(base + 1, N - 1);
        int r2 = min(base + 2, N - 1);
        int r3 = min(base + 3, N - 1);
        const float* x0 = x + (size_t)r0 * F1;
        const float* x1 = x + (size_t)r1 * F1;
        const float* x2 = x + (size_t)r2 * F1;
        const float* x3 = x + (size_t)r3 * F1;
        float a00 = 0, a01 = 0, a10 = 0, a11 = 0, a20 = 0, a21 = 0, a30 = 0, a31 = 0;
#pragma unroll 2
        for (int k = 0; k < F1; k += 4) {
            float4 xv0 = *(const float4*)(x0 + k);
            float4 xv1 = *(const float4*)(x1 + k);
            float4 xv2 = *(const float4*)(x2 + k);
            float4 xv3 = *(const float4*)(x3 + k);
#pragma unroll
            for (int kk = 0; kk < 4; kk++) {
                float2 wv = *((const float2*)&sW[(k + kk) * F1] + lane);
                float xs;
                xs = ((const float*)&xv0)[kk]; a00 = fmaf(xs, wv.x, a00); a01 = fmaf(xs, wv.y, a01);
                xs = ((const float*)&xv1)[kk]; a10 = fmaf(xs, wv.x, a10); a11 = fmaf(xs, wv.y, a11);
                xs = ((const float*)&xv2)[kk]; a20 = fmaf(xs, wv.x, a20); a21 = fmaf(xs, wv.y, a21);
                xs = ((const float*)&xv3)[kk]; a30 = fmaf(xs, wv.x, a30); a31 = fmaf(xs, wv.y, a31);
            }
        }
        float d;
        d = dis[r0];
        *((float2*)&g[(size_t)r0 * F1] + lane) = make_float2(a00 * d, a01 * d);
        if (base + 1 < N) { d = dis[r1]; *((float2*)&g[(size_t)r1 * F1] + lane) = make_float2(a10 * d, a11 * d); }
        if (base + 2 < N) { d = dis[r2]; *((float2*)&g[(size_t)r2 * F1] + lane) = make_float2(a20 * d, a21 * d); }
        if (base + 3 < N) { d = dis[r3]; *((float2*)&g[(size_t)r3 * F1] + lane) = make_float2(a30 * d, a31 * d); }
    }
}

// ---------------- Aggregation 1: z = relu(dis[i]*(g1[i] + sum g1[src]) + b1) ----------------

__global__ __launch_bounds__(256) void k_agg1(const float* __restrict__ g1,
                                              const int* __restrict__ rowptr,
                                              const int* __restrict__ adj,
                                              const float* __restrict__ dis,
                                              const float* __restrict__ b,
                                              float* __restrict__ z, int N) {
    int node = __builtin_amdgcn_readfirstlane(blockIdx.x * 4 + (threadIdx.x >> 6));
    if (node >= N) return;
    int lane = threadIdx.x & 63;
    const float2* gsrc = (const float2*)g1;   // row stride = 64 float2
    float2 acc = gsrc[(size_t)node * 64 + lane];   // self-loop term
    int s = rowptr[node], e = rowptr[node + 1];
    int j = s;
    for (; j + 3 < e; j += 4) {
        int s0 = adj[j], s1 = adj[j + 1], s2 = adj[j + 2], s3 = adj[j + 3];
        float2 v0 = gsrc[(size_t)s0 * 64 + lane];
        float2 v1 = gsrc[(size_t)s1 * 64 + lane];
        float2 v2 = gsrc[(size_t)s2 * 64 + lane];
        float2 v3 = gsrc[(size_t)s3 * 64 + lane];
        acc.x += (v0.x + v1.x) + (v2.x + v3.x);
        acc.y += (v0.y + v1.y) + (v2.y + v3.y);
    }
    for (; j < e; j++) {
        float2 v = gsrc[(size_t)adj[j] * 64 + lane];
        acc.x += v.x; acc.y += v.y;
    }
    float d = dis[node];
    float2 bb = ((const float2*)b)[lane];
    float2 o;
    o.x = fmaxf(fmaf(d, acc.x, bb.x), 0.0f);
    o.y = fmaxf(fmaf(d, acc.y, bb.y), 0.0f);
    ((float2*)z)[(size_t)node * 64 + lane] = o;
}

// ---------------- GEMM 2: g2 = dis[row] * (z @ W2), W2 128x64 in LDS ----------------
// block=256 (4 waves), LDS 32KB -> 5 blocks/CU = 20 waves/CU. VGPR cap ~102.
// 8 rows/wave so each ds_read_b32 of W feeds 8 FMAs.

__global__ __launch_bounds__(256, 5) void k_gemm2(const float* __restrict__ z,
                                                  const float* __restrict__ W,
                                                  const float* __restrict__ dis,
                                                  float* __restrict__ g, int N) {
    __shared__ float sW[F1 * F2];   // 32 KB
    {
        const float4* W4 = (const float4*)W;
        float4* s4 = (float4*)sW;
        for (int i = threadIdx.x; i < F1 * F2 / 4; i += 256) s4[i] = W4[i];
    }
    __syncthreads();
    int lane = threadIdx.x & 63;
    int wid = __builtin_amdgcn_readfirstlane(blockIdx.x * 4 + (threadIdx.x >> 6));
    int nw = gridDim.x * 4;
    int groups = (N + 7) >> 3;
    for (int grp = wid; grp < groups; grp += nw) {
        int base = grp * 8;
        const float* xr[8];
#pragma unroll
        for (int i = 0; i < 8; i++) {
            int r = min(base + i, N - 1);
            xr[i] = z + (size_t)r * F1;
        }
        float acc[8] = {0, 0, 0, 0, 0, 0, 0, 0};
#pragma unroll 1
        for (int k = 0; k < F1; k += 4) {
            float4 xv[8];
#pragma unroll
            for (int i = 0; i < 8; i++) xv[i] = *(const float4*)(xr[i] + k);
#pragma unroll
            for (int kk = 0; kk < 4; kk++) {
                float wv = sW[(k + kk) * F2 + lane];
#pragma unroll
                for (int i = 0; i < 8; i++)
                    acc[i] = fmaf(((const float*)&xv[i])[kk], wv, acc[i]);
            }
        }
#pragma unroll
        for (int i = 0; i < 8; i++) {
            int r = base + i;
            if (r < N) g[(size_t)r * F2 + lane] = acc[i] * dis[r];
        }
    }
}

// ---------------- Aggregation 2: out = dis[i]*(g2[i] + sum g2[src]) + b2 ----------------

__global__ __launch_bounds__(256) void k_agg2(const float* __restrict__ g,
                                              const int* __restrict__ rowptr,
                                              const int* __restrict__ adj,
                                              const float* __restrict__ dis,
                                              const float* __restrict__ b,
                                              float* __restrict__ out, int N) {
    int node = __builtin_amdgcn_readfirstlane(blockIdx.x * 4 + (threadIdx.x >> 6));
    if (node >= N) return;
    int lane = threadIdx.x & 63;
    float acc = g[(size_t)node * F2 + lane];   // self-loop term
    int s = rowptr[node], e = rowptr[node + 1];
    int j = s;
    for (; j + 3 < e; j += 4) {
        int s0 = adj[j], s1 = adj[j + 1], s2 = adj[j + 2], s3 = adj[j + 3];
        float v0 = g[(size_t)s0 * F2 + lane];
        float v1 = g[(size_t)s1 * F2 + lane];
        float v2 = g[(size_t)s2 * F2 + lane];
        float v3 = g[(size_t)s3 * F2 + lane];
        acc += (v0 + v1) + (v2 + v3);
    }
    for (; j < e; j++) acc += g[(size_t)adj[j] * F2 + lane];
    out[(size_t)node * F2 + lane] = fmaf(dis[node], acc, b[lane]);
}

// ---------------- launch ----------------

extern "C" void kernel_launch(void* const* d_in, const int* in_sizes, int n_in,
                              void* d_out, int out_size, void* d_ws, size_t ws_size,
                              hipStream_t stream) {
    const float* x  = (const float*)d_in[0];
    const int*   ei = (const int*)d_in[1];
    const float* W1 = (const float*)d_in[2];
    const float* b1 = (const float*)d_in[3];
    const float* W2 = (const float*)d_in[4];
    const float* b2 = (const float*)d_in[5];
    float* out = (float*)d_out;

    const int N = in_sizes[0] / F1;
    const int E = in_sizes[1] / 2;
    const int* rowv = ei;        // sources
    const int* colv = ei + E;    // targets

    char* ws = (char*)d_ws;
    size_t off = 0;
    auto take = [&](size_t bytes) -> void* {
        void* p = ws + off;
        off += (bytes + 255) & ~(size_t)255;
        return p;
    };
    float* g1      = (float*)take((size_t)N * F1 * 4);   // 51.2 MB
    float* z       = (float*)take((size_t)N * F1 * 4);   // 51.2 MB
    float* g2      = g1;                                  // g1 dead after agg1 -> reuse
    float* dis     = (float*)take((size_t)N * 4);
    int*   counts  = (int*)take((size_t)N * 4);
    int*   rowptr  = (int*)take((size_t)(N + 1) * 4);
    int*   cursor  = (int*)take((size_t)N * 4);
    int*   partials= (int*)take(1024 * 4);
    int*   adj     = (int*)take((size_t)E * 4);          // 6.4 MB

    hipMemsetAsync(counts, 0, (size_t)N * 4, stream);

    k_hist<<<(E + 255) / 256, 256, 0, stream>>>(colv, counts, E);
    int P = (N + 1023) / 1024;
    k_scan1<<<P, 1024, 0, stream>>>(counts, rowptr, partials, N);
    k_scan2<<<1, 64, 0, stream>>>(partials, P, rowptr + N);
    k_scan3<<<(N + 255) / 256, 256, 0, stream>>>(rowptr, cursor, partials, N);
    k_fill<<<(E + 255) / 256, 256, 0, stream>>>(rowv, colv, cursor, adj, E);
    k_dis<<<(N + 255) / 256, 256, 0, stream>>>(counts, dis, N);

    k_gemm1<<<512, 512, 0, stream>>>(x, W1, dis, g1, N);
    k_agg1<<<(N + 3) / 4, 256, 0, stream>>>(g1, rowptr, adj, dis, b1, z, N);
    k_gemm2<<<1280, 256, 0, stream>>>(z, W2, dis, g2, N);
    k_agg2<<<(N + 3) / 4, 256, 0, stream>>>(g2, rowptr, adj, dis, b2, out, N);
}

// Round 3
// 530.500 us; speedup vs baseline: 1.5809x; 1.2887x over previous
//
#include <hip/hip_runtime.h>

#define F1 128
#define F2 64
// bucket = 512 consecutive nodes; requires N <= 256*512
#define BSH 9
#define BSZ 512

typedef unsigned long long u64;

// ---------------- CSR build (bucketed, LDS atomics) ----------------

__global__ __launch_bounds__(256) void k_bhist(const int* __restrict__ colv,
                                               int* __restrict__ bucket_cnt, int E) {
    __shared__ int l[256];
    int t = threadIdx.x;
    l[t] = 0;
    __syncthreads();
    for (int e = blockIdx.x * blockDim.x + t; e < E; e += gridDim.x * blockDim.x)
        atomicAdd(&l[colv[e] >> BSH], 1);
    __syncthreads();
    if (l[t]) atomicAdd(&bucket_cnt[t], l[t]);
}

__global__ __launch_bounds__(256) void k_bscan(const int* __restrict__ bucket_cnt,
                                               int* __restrict__ bucket_base,
                                               int* __restrict__ bucket_cur,
                                               int* __restrict__ rowptr_last,
                                               int NB, int E) {
    __shared__ int s[256];
    int t = threadIdx.x;
    int v = (t < NB) ? bucket_cnt[t] : 0;
    s[t] = v;
    __syncthreads();
    for (int d = 1; d < 256; d <<= 1) {
        int u = (t >= d) ? s[t - d] : 0;
        __syncthreads();
        s[t] += u;
        __syncthreads();
    }
    int excl = s[t] - v;
    if (t < NB) { bucket_base[t] = excl; bucket_cur[t] = excl; }
    if (t == NB - 1) bucket_base[NB] = s[t];
    if (t == 0) *rowptr_last = E;
}

// Each block stages CHUNK=4096 edges in registers, reserves per-bucket runs with
// ONE global atomic per bucket, then writes packed (col<<32|row) bucket-major.
__global__ __launch_bounds__(256) void k_part(const int* __restrict__ rowv,
                                              const int* __restrict__ colv,
                                              int* __restrict__ bucket_cur,
                                              u64* __restrict__ ebuf, int E) {
    __shared__ int lcnt[256], lbase[256], loff[256];
    int t = threadIdx.x;
    lcnt[t] = 0; loff[t] = 0;
    __syncthreads();
    int rows[16], cols[16];
    int e0 = blockIdx.x * 4096;
#pragma unroll
    for (int it = 0; it < 16; it++) {
        int e = e0 + it * 256 + t;
        bool v = e < E;
        cols[it] = v ? colv[e] : -1;
        rows[it] = v ? rowv[e] : 0;
        if (v) atomicAdd(&lcnt[cols[it] >> BSH], 1);
    }
    __syncthreads();
    if (lcnt[t]) lbase[t] = atomicAdd(&bucket_cur[t], lcnt[t]);
    __syncthreads();
#pragma unroll
    for (int it = 0; it < 16; it++) {
        if (cols[it] >= 0) {
            int b = cols[it] >> BSH;
            int p = lbase[b] + atomicAdd(&loff[b], 1);
            ebuf[p] = ((u64)(unsigned)cols[it] << 32) | (unsigned)rows[it];
        }
    }
}

// One block per bucket: per-node counts + scan + placement all via LDS.
// Writes rowptr, dis, adj for its 512-node window.
__global__ __launch_bounds__(512) void k_bfill(const u64* __restrict__ ebuf,
                                               const int* __restrict__ bucket_base,
                                               int* __restrict__ rowptr,
                                               float* __restrict__ dis,
                                               int* __restrict__ adj, int N) {
    __shared__ int cnt[BSZ], scn[BSZ], cur[BSZ];
    int t = threadIdx.x;
    int b = blockIdx.x;
    int e0 = bucket_base[b], e1 = bucket_base[b + 1];
    cnt[t] = 0;
    __syncthreads();
    for (int i = e0 + t; i < e1; i += BSZ) {
        int c = (int)(ebuf[i] >> 32);
        atomicAdd(&cnt[c & (BSZ - 1)], 1);
    }
    __syncthreads();
    scn[t] = cnt[t];
    __syncthreads();
    for (int d = 1; d < BSZ; d <<= 1) {
        int u = (t >= d) ? scn[t - d] : 0;
        __syncthreads();
        scn[t] += u;
        __syncthreads();
    }
    int excl = scn[t] - cnt[t];
    cur[t] = excl;
    int node = (b << BSH) + t;
    if (node < N) {
        rowptr[node] = e0 + excl;
        dis[node] = rsqrtf((float)(cnt[t] + 1));   // +1 self loop
    }
    __syncthreads();
    for (int i = e0 + t; i < e1; i += BSZ) {
        u64 p = ebuf[i];
        int c = (int)(p >> 32) & (BSZ - 1);
        int r = (int)(unsigned)p;
        int pos = atomicAdd(&cur[c], 1);
        adj[e0 + pos] = r;
    }
}

// ---------------- GEMM 1: g1 = dis[row] * (x @ W1), W1 128x128 in LDS ----------------

__global__ __launch_bounds__(512, 4) void k_gemm1(const float* __restrict__ x,
                                                  const float* __restrict__ W,
                                                  const float* __restrict__ dis,
                                                  float* __restrict__ g, int N) {
    __shared__ float sW[F1 * F1];   // 64 KB
    {
        const float4* W4 = (const float4*)W;
        float4* s4 = (float4*)sW;
        for (int i = threadIdx.x; i < F1 * F1 / 4; i += 512) s4[i] = W4[i];
    }
    __syncthreads();
    int lane = threadIdx.x & 63;
    int wid = __builtin_amdgcn_readfirstlane(blockIdx.x * 8 + (threadIdx.x >> 6));
    int nw = gridDim.x * 8;
    int groups = (N + 3) >> 2;
    for (int grp = wid; grp < groups; grp += nw) {
        int base = grp * 4;
        int r0 = base;
        int r1 = min(base + 1, N - 1);
        int r2 = min(base + 2, N - 1);
        int r3 = min(base + 3, N - 1);
        const float* x0 = x + (size_t)r0 * F1;
        const float* x1 = x + (size_t)r1 * F1;
        const float* x2 = x + (size_t)r2 * F1;
        const float* x3 = x + (size_t)r3 * F1;
        float a00 = 0, a01 = 0, a10 = 0, a11 = 0, a20 = 0, a21 = 0, a30 = 0, a31 = 0;
#pragma unroll 2
        for (int k = 0; k < F1; k += 4) {
            float4 xv0 = *(const float4*)(x0 + k);
            float4 xv1 = *(const float4*)(x1 + k);
            float4 xv2 = *(const float4*)(x2 + k);
            float4 xv3 = *(const float4*)(x3 + k);
#pragma unroll
            for (int kk = 0; kk < 4; kk++) {
                float2 wv = *((const float2*)&sW[(k + kk) * F1] + lane);
                float xs;
                xs = ((const float*)&xv0)[kk]; a00 = fmaf(xs, wv.x, a00); a01 = fmaf(xs, wv.y, a01);
                xs = ((const float*)&xv1)[kk]; a10 = fmaf(xs, wv.x, a10); a11 = fmaf(xs, wv.y, a11);
                xs = ((const float*)&xv2)[kk]; a20 = fmaf(xs, wv.x, a20); a21 = fmaf(xs, wv.y, a21);
                xs = ((const float*)&xv3)[kk]; a30 = fmaf(xs, wv.x, a30); a31 = fmaf(xs, wv.y, a31);
            }
        }
        float d;
        d = dis[r0];
        *((float2*)&g[(size_t)r0 * F1] + lane) = make_float2(a00 * d, a01 * d);
        if (base + 1 < N) { d = dis[r1]; *((float2*)&g[(size_t)r1 * F1] + lane) = make_float2(a10 * d, a11 * d); }
        if (base + 2 < N) { d = dis[r2]; *((float2*)&g[(size_t)r2 * F1] + lane) = make_float2(a20 * d, a21 * d); }
        if (base + 3 < N) { d = dis[r3]; *((float2*)&g[(size_t)r3 * F1] + lane) = make_float2(a30 * d, a31 * d); }
    }
}

// ---------------- Aggregation 1: z = relu(dis[i]*(g1[i] + sum g1[src]) + b1) ----------------

__global__ __launch_bounds__(256) void k_agg1(const float* __restrict__ g1,
                                              const int* __restrict__ rowptr,
                                              const int* __restrict__ adj,
                                              const float* __restrict__ dis,
                                              const float* __restrict__ b,
                                              float* __restrict__ z, int N) {
    int node = __builtin_amdgcn_readfirstlane(blockIdx.x * 4 + (threadIdx.x >> 6));
    if (node >= N) return;
    int lane = threadIdx.x & 63;
    const float2* gsrc = (const float2*)g1;   // row stride = 64 float2
    float2 acc = gsrc[(size_t)node * 64 + lane];   // self-loop term
    int s = rowptr[node], e = rowptr[node + 1];
    int j = s;
    for (; j + 3 < e; j += 4) {
        int s0 = adj[j], s1 = adj[j + 1], s2 = adj[j + 2], s3 = adj[j + 3];
        float2 v0 = gsrc[(size_t)s0 * 64 + lane];
        float2 v1 = gsrc[(size_t)s1 * 64 + lane];
        float2 v2 = gsrc[(size_t)s2 * 64 + lane];
        float2 v3 = gsrc[(size_t)s3 * 64 + lane];
        acc.x += (v0.x + v1.x) + (v2.x + v3.x);
        acc.y += (v0.y + v1.y) + (v2.y + v3.y);
    }
    for (; j < e; j++) {
        float2 v = gsrc[(size_t)adj[j] * 64 + lane];
        acc.x += v.x; acc.y += v.y;
    }
    float d = dis[node];
    float2 bb = ((const float2*)b)[lane];
    float2 o;
    o.x = fmaxf(fmaf(d, acc.x, bb.x), 0.0f);
    o.y = fmaxf(fmaf(d, acc.y, bb.y), 0.0f);
    ((float2*)z)[(size_t)node * 64 + lane] = o;
}

// ---------------- GEMM 2: g2 = dis[row] * (z @ W2), W2 128x64 in LDS ----------------

__global__ __launch_bounds__(256, 5) void k_gemm2(const float* __restrict__ z,
                                                  const float* __restrict__ W,
                                                  const float* __restrict__ dis,
                                                  float* __restrict__ g, int N) {
    __shared__ float sW[F1 * F2];   // 32 KB
    {
        const float4* W4 = (const float4*)W;
        float4* s4 = (float4*)sW;
        for (int i = threadIdx.x; i < F1 * F2 / 4; i += 256) s4[i] = W4[i];
    }
    __syncthreads();
    int lane = threadIdx.x & 63;
    int wid = __builtin_amdgcn_readfirstlane(blockIdx.x * 4 + (threadIdx.x >> 6));
    int nw = gridDim.x * 4;
    int groups = (N + 7) >> 3;
    for (int grp = wid; grp < groups; grp += nw) {
        int base = grp * 8;
        const float* xr[8];
#pragma unroll
        for (int i = 0; i < 8; i++) {
            int r = min(base + i, N - 1);
            xr[i] = z + (size_t)r * F1;
        }
        float acc[8] = {0, 0, 0, 0, 0, 0, 0, 0};
#pragma unroll 1
        for (int k = 0; k < F1; k += 4) {
            float4 xv[8];
#pragma unroll
            for (int i = 0; i < 8; i++) xv[i] = *(const float4*)(xr[i] + k);
#pragma unroll
            for (int kk = 0; kk < 4; kk++) {
                float wv = sW[(k + kk) * F2 + lane];
#pragma unroll
                for (int i = 0; i < 8; i++)
                    acc[i] = fmaf(((const float*)&xv[i])[kk], wv, acc[i]);
            }
        }
#pragma unroll
        for (int i = 0; i < 8; i++) {
            int r = base + i;
            if (r < N) g[(size_t)r * F2 + lane] = acc[i] * dis[r];
        }
    }
}

// ---------------- Aggregation 2: out = dis[i]*(g2[i] + sum g2[src]) + b2 ----------------

__global__ __launch_bounds__(256) void k_agg2(const float* __restrict__ g,
                                              const int* __restrict__ rowptr,
                                              const int* __restrict__ adj,
                                              const float* __restrict__ dis,
                                              const float* __restrict__ b,
                                              float* __restrict__ out, int N) {
    int node = __builtin_amdgcn_readfirstlane(blockIdx.x * 4 + (threadIdx.x >> 6));
    if (node >= N) return;
    int lane = threadIdx.x & 63;
    float acc = g[(size_t)node * F2 + lane];   // self-loop term
    int s = rowptr[node], e = rowptr[node + 1];
    int j = s;
    for (; j + 3 < e; j += 4) {
        int s0 = adj[j], s1 = adj[j + 1], s2 = adj[j + 2], s3 = adj[j + 3];
        float v0 = g[(size_t)s0 * F2 + lane];
        float v1 = g[(size_t)s1 * F2 + lane];
        float v2 = g[(size_t)s2 * F2 + lane];
        float v3 = g[(size_t)s3 * F2 + lane];
        acc += (v0 + v1) + (v2 + v3);
    }
    for (; j < e; j++) acc += g[(size_t)adj[j] * F2 + lane];
    out[(size_t)node * F2 + lane] = fmaf(dis[node], acc, b[lane]);
}

// ---------------- launch ----------------

extern "C" void kernel_launch(void* const* d_in, const int* in_sizes, int n_in,
                              void* d_out, int out_size, void* d_ws, size_t ws_size,
                              hipStream_t stream) {
    const float* x  = (const float*)d_in[0];
    const int*   ei = (const int*)d_in[1];
    const float* W1 = (const float*)d_in[2];
    const float* b1 = (const float*)d_in[3];
    const float* W2 = (const float*)d_in[4];
    const float* b2 = (const float*)d_in[5];
    float* out = (float*)d_out;

    const int N = in_sizes[0] / F1;
    const int E = in_sizes[1] / 2;
    const int NB = (N + BSZ - 1) >> BSH;   // 196 for N=100000; must be <= 256
    const int* rowv = ei;        // sources
    const int* colv = ei + E;    // targets

    char* ws = (char*)d_ws;
    size_t off = 0;
    auto take = [&](size_t bytes) -> void* {
        void* p = ws + off;
        off += (bytes + 255) & ~(size_t)255;
        return p;
    };
    float* g1      = (float*)take((size_t)N * F1 * 4);   // 51.2 MB
    float* z       = (float*)take((size_t)N * F1 * 4);   // 51.2 MB
    float* g2      = g1;                 // g1 dead after agg1 -> reuse
    u64*   ebuf    = (u64*)g1;           // ebuf (12.8 MB) dead before gemm1 writes g1
    float* dis     = (float*)take((size_t)N * 4);
    int*   rowptr  = (int*)take((size_t)(N + 1) * 4);
    int*   adj     = (int*)take((size_t)E * 4);          // 6.4 MB
    int*   bucket_cnt  = (int*)take(256 * 4);
    int*   bucket_base = (int*)take(257 * 4);
    int*   bucket_cur  = (int*)take(256 * 4);

    hipMemsetAsync(bucket_cnt, 0, 256 * 4, stream);

    k_bhist<<<256, 256, 0, stream>>>(colv, bucket_cnt, E);
    k_bscan<<<1, 256, 0, stream>>>(bucket_cnt, bucket_base, bucket_cur, rowptr + N, NB, E);
    k_part<<<(E + 4095) / 4096, 256, 0, stream>>>(rowv, colv, bucket_cur, ebuf, E);
    k_bfill<<<NB, BSZ, 0, stream>>>(ebuf, bucket_base, rowptr, dis, adj, N);

    k_gemm1<<<512, 512, 0, stream>>>(x, W1, dis, g1, N);
    k_agg1<<<(N + 3) / 4, 256, 0, stream>>>(g1, rowptr, adj, dis, b1, z, N);
    k_gemm2<<<1280, 256, 0, stream>>>(z, W2, dis, g2, N);
    k_agg2<<<(N + 3) / 4, 256, 0, stream>>>(g2, rowptr, adj, dis, b2, out, N);
}